// Round 2
// baseline (2426.133 us; speedup 1.0000x reference)
//
#include <hip/hip_runtime.h>
#include <hip/hip_bf16.h>
#include <math.h>

#define S 512
#define B 8
#define H 768
#define NH 12
#define DH 64
#define DV 192
#define II 2304
#define NL 4
#define SCALE 0.07216878364870322f
#define EPS 1e-7f

typedef __attribute__((ext_vector_type(8))) short short8;
typedef __attribute__((ext_vector_type(4))) float f32x4;

__device__ __forceinline__ float b2f(ushort u){
  union { float f; unsigned int u; } v; v.u = ((unsigned int)u) << 16; return v.f;
}
__device__ __forceinline__ ushort f2b(float f){
  union { float f; unsigned int u; } v; v.f = f;
  unsigned int u = v.u;
  return (ushort)((u + 0x7fffu + ((u >> 16) & 1u)) >> 16);
}
__device__ __forceinline__ float gelu_f(float x){
  return 0.5f * x * (1.0f + erff(x * 0.70710678118654752f));
}

// ---- block-wide sum of two floats across 256 threads (4 waves) ----
__device__ __forceinline__ void block_sum2(float& s, float& s2, float* red, int t){
  #pragma unroll
  for(int off=32; off>=1; off>>=1){ s += __shfl_xor(s, off); s2 += __shfl_xor(s2, off); }
  int w = t >> 6;
  if((t & 63) == 0){ red[w] = s; red[4 + w] = s2; }
  __syncthreads();
  s  = red[0] + red[1] + red[2] + red[3];
  s2 = red[4] + red[5] + red[6] + red[7];
}

// ---- f32 -> bf16 bulk convert (n divisible by 1024) ----
__global__ __launch_bounds__(256)
void f2b_kernel(const float* __restrict__ in, ushort* __restrict__ out){
  int i = (blockIdx.x * 256 + threadIdx.x) * 4;
  float4 v = *(const float4*)(in + i);
  __attribute__((aligned(8))) ushort tmp[4] = { f2b(v.x), f2b(v.y), f2b(v.z), f2b(v.w) };
  *(uint2*)(out + i) = *(const uint2*)tmp;
}

// ---- x = LN(word_emb[ids])  (f32 in, f32 out) ----
__global__ __launch_bounds__(256)
void embed_ln_kernel(const int* __restrict__ ids, const float* __restrict__ wemb,
                     float* __restrict__ x)
{
  __shared__ float red[8];
  const int sb = blockIdx.x, t = threadIdx.x;
  const float* row = wemb + (size_t)ids[sb] * H;
  float v0 = row[t], v1 = row[t+256], v2 = row[t+512];
  float s = v0+v1+v2, s2 = v0*v0+v1*v1+v2*v2;
  block_sum2(s, s2, red, t);
  float mean = s * (1.0f/H);
  float rstd = rsqrtf(s2*(1.0f/H) - mean*mean + EPS);
  float* xo = x + (size_t)sb * H;
  xo[t]     = (v0-mean)*rstd;
  xo[t+256] = (v1-mean)*rstd;
  xo[t+512] = (v2-mean)*rstd;
}

// ---- relb = LN(rel_emb)*w + b  (f32 in, bf16 out) ----
__global__ __launch_bounds__(256)
void rel_ln_kernel(const float* __restrict__ rel_emb, const float* __restrict__ w,
                   const float* __restrict__ bia, ushort* __restrict__ outb)
{
  __shared__ float red[8];
  const int j = blockIdx.x, t = threadIdx.x;
  const float* row = rel_emb + (size_t)j * H;
  float v0=row[t], v1=row[t+256], v2=row[t+512];
  float s=v0+v1+v2, s2=v0*v0+v1*v1+v2*v2;
  block_sum2(s,s2,red,t);
  float mean = s*(1.0f/H);
  float rstd = rsqrtf(s2*(1.0f/H)-mean*mean+EPS);
  ushort* o = outb + (size_t)j*H;
  o[t]     = f2b((v0-mean)*rstd * w[t]     + bia[t]);
  o[t+256] = f2b((v1-mean)*rstd * w[t+256] + bia[t+256]);
  o[t+512] = f2b((v2-mean)*rstd * w[t+512] + bia[t+512]);
}

// ---- h = LN(x)  (bf16 out) ----
__global__ __launch_bounds__(256)
void ln_x_kernel(const float* __restrict__ x, ushort* __restrict__ h)
{
  __shared__ float red[8];
  const int sb = blockIdx.x, t = threadIdx.x;
  const float* row = x + (size_t)sb * H;
  float v0 = row[t], v1 = row[t+256], v2 = row[t+512];
  float s = v0+v1+v2, s2 = v0*v0+v1*v1+v2*v2;
  block_sum2(s, s2, red, t);
  float mean = s * (1.0f/H);
  float rstd = rsqrtf(s2*(1.0f/H) - mean*mean + EPS);
  ushort* o = h + (size_t)sb * H;
  o[t]     = f2b((v0-mean)*rstd);
  o[t+256] = f2b((v1-mean)*rstd);
  o[t+512] = f2b((v2-mean)*rstd);
}

// ---- GEMM: C[m][n] = sum_k A[m][k]*Bw[n][k] (+bias[n]); A,Bw bf16 row-major ----
// OUT_MODE: 0 = f32 store, 1 = bf16 store, 2 = f32 accumulate (+=)
template<int OUT_MODE>
__global__ __launch_bounds__(256)
void gemm_nt(const ushort* __restrict__ A, const ushort* __restrict__ Bw,
             const float* __restrict__ bias, void* __restrict__ Cout,
             int M, int N, int K)
{
  __shared__ ushort As[64][40];
  __shared__ ushort Bs[64][40];
  const int n0 = blockIdx.x * 64, m0 = blockIdx.y * 64;
  const int t = threadIdx.x;
  const int lrow = t >> 2, lk = (t & 3) * 8;
  const int lane = t & 63, w = t >> 6, lr = lane & 15, lq = lane >> 4;
  const int wr = (w >> 1) * 32, wc = (w & 1) * 32;
  f32x4 z = {0.f,0.f,0.f,0.f};
  f32x4 acc[2][2] = {{z,z},{z,z}};
  const int arow = m0 + lrow;
  const ushort* aptr = A  + (size_t)arow * K + lk;
  const ushort* bptr = Bw + (size_t)(n0 + lrow) * K + lk;
  for(int k0 = 0; k0 < K; k0 += 32){
    short8 av = {0,0,0,0,0,0,0,0};
    if(arow < M) av = *(const short8*)(aptr + k0);
    short8 bv = *(const short8*)(bptr + k0);
    __syncthreads();
    *(short8*)&As[lrow][lk] = av;
    *(short8*)&Bs[lrow][lk] = bv;
    __syncthreads();
    short8 a0 = *(const short8*)&As[wr + lr][lq * 8];
    short8 a1 = *(const short8*)&As[wr + 16 + lr][lq * 8];
    short8 b0 = *(const short8*)&Bs[wc + lr][lq * 8];
    short8 b1 = *(const short8*)&Bs[wc + 16 + lr][lq * 8];
    acc[0][0] = __builtin_amdgcn_mfma_f32_16x16x32_bf16(a0, b0, acc[0][0], 0,0,0);
    acc[0][1] = __builtin_amdgcn_mfma_f32_16x16x32_bf16(a0, b1, acc[0][1], 0,0,0);
    acc[1][0] = __builtin_amdgcn_mfma_f32_16x16x32_bf16(a1, b0, acc[1][0], 0,0,0);
    acc[1][1] = __builtin_amdgcn_mfma_f32_16x16x32_bf16(a1, b1, acc[1][1], 0,0,0);
  }
  #pragma unroll
  for(int i=0;i<2;i++){
    #pragma unroll
    for(int j=0;j<2;j++){
      #pragma unroll
      for(int r=0;r<4;r++){
        int m = m0 + wr + i*16 + lq*4 + r;
        int n = n0 + wc + j*16 + lr;
        if(m >= M) continue;
        float v = acc[i][j][r];
        if(bias) v += bias[n];
        if(OUT_MODE == 0)      ((float*) Cout)[(size_t)m*N + n] = v;
        else if(OUT_MODE == 1) ((ushort*)Cout)[(size_t)m*N + n] = f2b(v);
        else                   ((float*) Cout)[(size_t)m*N + n] += v;
      }
    }
  }
}

// ---- cp[q,b,h,j] = q4(q,b,h)·kpos(j,h);  cq[k,b,h,j] = k4(k,b,h)·qpos(j,h) ----
__global__ __launch_bounds__(256)
void cpq_kernel(const ushort* __restrict__ qk, const float* __restrict__ pos,
                float* __restrict__ cp, float* __restrict__ cq)
{
  const int sb = blockIdx.x, t = threadIdx.x;
  __shared__ float qr[768];
  __shared__ float kr[768];
  const ushort* base = qk + (size_t)sb * 1536;
  for(int i=t; i<768; i+=256){ qr[i]=b2f(base[i]); kr[i]=b2f(base[768+i]); }
  __syncthreads();
  for(int task=t; task<1512; task+=256){
    int which = (task >= 756) ? 1 : 0;
    int rem = task - which*756;
    int hh = rem/63, j = rem - hh*63;
    const float4* pv = (const float4*)(pos + (size_t)j*1536 + (which ? 0 : 768) + hh*64);
    const float4* xv = (const float4*)((which ? kr : qr) + hh*64);
    float acc = 0.f;
    #pragma unroll
    for(int d=0; d<16; d++){
      float4 a = xv[d], p = pv[d];
      acc += a.x*p.x + a.y*p.y + a.z*p.z + a.w*p.w;
    }
    (which ? cq : cp)[((size_t)sb*NH + hh)*63 + j] = acc;
  }
}

// ---- Vt[b][h][v][s] = value[s][b][h*DV+v]  (bf16) ----
__global__ __launch_bounds__(256)
void vt_kernel(const ushort* __restrict__ vg, ushort* __restrict__ vt)
{
  const int st = blockIdx.x, hh = blockIdx.y, b = blockIdx.z;
  __shared__ ushort tile[32][200];
  const int t = threadIdx.x;
  {
    int sl = t >> 3, v0 = (t & 7) * 24;
    const ushort* src = vg + ((size_t)((st*32 + sl)*B + b))*(2*II) + hh*DV + v0;
    *(short8*)&tile[sl][v0]      = *(const short8*)(src);
    *(short8*)&tile[sl][v0 + 8]  = *(const short8*)(src + 8);
    *(short8*)&tile[sl][v0 + 16] = *(const short8*)(src + 16);
  }
  __syncthreads();
  if(t < DV){
    __attribute__((aligned(16))) ushort tmp[32];
    #pragma unroll
    for(int s2=0;s2<32;s2++) tmp[s2] = tile[s2][t];
    ushort* dst = vt + (((size_t)(b*NH + hh))*DV + t)*S + st*32;
    #pragma unroll
    for(int c=0;c<32;c+=8) *(short8*)(dst + c) = *(const short8*)&tmp[c];
  }
}

// ---- fused attention: scores(MFMA)+rel-pos gathers+softmax+PV(MFMA) ----
__global__ __launch_bounds__(256)
void attn_kernel(const ushort* __restrict__ qk, const ushort* __restrict__ vt,
                 const float* __restrict__ cp, const float* __restrict__ cq,
                 const int* __restrict__ pidx, ushort* __restrict__ ctx)
{
  const int qt = blockIdx.x, hh = blockIdx.y, b = blockIdx.z;
  __shared__ ushort Qs[16][72];
  __shared__ ushort Ps[16][520];
  __shared__ float cps[16][64];
  __shared__ float redm[4][16];
  __shared__ float reds[4][16];
  __shared__ float rowinv[16];
  const int t = threadIdx.x, w = t>>6, lane = t&63, lr = lane&15, lq = lane>>4;

  {
    int r = t >> 4, d0 = (t & 15) * 4;
    const ushort* src = qk + ((size_t)((qt*16 + r)*B + b))*1536 + hh*DH + d0;
    *(uint2*)&Qs[r][d0] = *(const uint2*)src;
  }
  for(int i=t; i<16*63; i+=256){
    int r = i/63, j = i - r*63;
    cps[r][j] = cp[(((size_t)(qt*16+r)*B + b)*NH + hh)*63 + j];
  }
  __syncthreads();

  // ---- phase 1: scores (this wave covers k in [w*128, w*128+128)) ----
  float sc[8][4];
  const int kbase = w * 128;
  #pragma unroll
  for(int tile=0; tile<8; tile++){
    const int k0 = kbase + tile*16;
    const ushort* kp = qk + ((size_t)((k0 + lr)*B + b))*1536 + H + hh*DH + lq*8;
    short8 b0 = *(const short8*)kp;
    short8 b1 = *(const short8*)(kp + 32);
    short8 a0 = *(const short8*)&Qs[lr][lq*8];
    short8 a1 = *(const short8*)&Qs[lr][32 + lq*8];
    f32x4 acc = {0.f,0.f,0.f,0.f};
    acc = __builtin_amdgcn_mfma_f32_16x16x32_bf16(a0, b0, acc, 0,0,0);
    acc = __builtin_amdgcn_mfma_f32_16x16x32_bf16(a1, b1, acc, 0,0,0);
    const int kcol = k0 + lr;
    #pragma unroll
    for(int r=0;r<4;r++){
      int ql = lq*4 + r;
      int pi = pidx[(qt*16+ql)*S + kcol];
      sc[tile][r] = (acc[r] + cps[ql][pi]
                     + cq[(((size_t)kcol*B + b)*NH + hh)*63 + pi]) * SCALE;
    }
  }

  // ---- softmax over k=512 (rows live in 16-lane groups + 4 waves) ----
  float gm[4], gs[4];
  #pragma unroll
  for(int r=0;r<4;r++){
    float m = sc[0][r];
    #pragma unroll
    for(int tile=1;tile<8;tile++) m = fmaxf(m, sc[tile][r]);
    #pragma unroll
    for(int off=1; off<16; off<<=1) m = fmaxf(m, __shfl_xor(m, off));
    if(lr==0) redm[w][lq*4+r] = m;
  }
  __syncthreads();
  #pragma unroll
  for(int r=0;r<4;r++){
    int row = lq*4+r;
    gm[r] = fmaxf(fmaxf(redm[0][row],redm[1][row]),fmaxf(redm[2][row],redm[3][row]));
  }
  #pragma unroll
  for(int r=0;r<4;r++){
    float s = 0.f;
    #pragma unroll
    for(int tile=0;tile<8;tile++){ float e = __expf(sc[tile][r]-gm[r]); sc[tile][r]=e; s+=e; }
    #pragma unroll
    for(int off=1; off<16; off<<=1) s += __shfl_xor(s, off);
    if(lr==0) reds[w][lq*4+r] = s;
  }
  __syncthreads();
  #pragma unroll
  for(int r=0;r<4;r++){
    int row = lq*4+r;
    gs[r] = reds[0][row]+reds[1][row]+reds[2][row]+reds[3][row];
    if(w==0 && lr==0) rowinv[row] = 1.0f/gs[r];
  }
  #pragma unroll
  for(int tile=0;tile<8;tile++){
    #pragma unroll
    for(int r=0;r<4;r++) Ps[lq*4+r][kbase + tile*16 + lr] = f2b(sc[tile][r]);
  }
  __syncthreads();

  // ---- phase 2: ctx = P @ V  (Vt[b][h][v][s] gives contiguous B-fragments) ----
  f32x4 z = {0.f,0.f,0.f,0.f};
  f32x4 acc2[3] = {z,z,z};
  const ushort* vbase = vt + ((size_t)(b*NH + hh))*DV*S;
  for(int kk=0; kk<S; kk+=32){
    short8 a = *(const short8*)&Ps[lr][kk + lq*8];
    #pragma unroll
    for(int ti=0; ti<3; ti++){
      const int v0 = (w*3 + ti)*16;
      short8 bv = *(const short8*)(vbase + (size_t)(v0 + lr)*S + kk + lq*8);
      acc2[ti] = __builtin_amdgcn_mfma_f32_16x16x32_bf16(a, bv, acc2[ti], 0,0,0);
    }
  }
  #pragma unroll
  for(int ti=0; ti<3; ti++){
    const int v0 = (w*3 + ti)*16;
    #pragma unroll
    for(int r=0;r<4;r++){
      int ql = lq*4 + r;
      float val = acc2[ti][r] * rowinv[ql];
      ctx[((size_t)((qt*16+ql)*B + b))*II + hh*DV + v0 + lr] = f2b(val);
    }
  }
}

// ---- ctx2 = LN( (ctx + sigmoid(lskip)*gelu(value)) * gelu(gate) )  (bf16) ----
__global__ __launch_bounds__(256)
void glu_ln_kernel(const ushort* __restrict__ ctx, const ushort* __restrict__ vg,
                   const float* __restrict__ ls, ushort* __restrict__ outb)
{
  __shared__ float red[8];
  const int sb = blockIdx.x, t = threadIdx.x;
  const ushort* crow = ctx + (size_t)sb*II;
  const ushort* vrow = vg + (size_t)sb*2*II;
  float c[9]; float s=0.f, s2=0.f;
  #pragma unroll
  for(int i=0;i<9;i++){
    int idx = t + i*256;
    float cv  = b2f(crow[idx]);
    float val = b2f(vrow[idx]);
    float gt  = b2f(vrow[II + idx]);
    float sk  = 1.0f/(1.0f + __expf(-ls[idx]));
    cv = (cv + sk*gelu_f(val)) * gelu_f(gt);
    c[i]=cv; s+=cv; s2+=cv*cv;
  }
  block_sum2(s,s2,red,t);
  float mean = s*(1.0f/II);
  float rstd = rsqrtf(s2*(1.0f/II)-mean*mean+EPS);
  ushort* o = outb + (size_t)sb*II;
  #pragma unroll
  for(int i=0;i<9;i++) o[t+i*256] = f2b((c[i]-mean)*rstd);
}

// ---- final copy x(f32) -> out(f32) ----
__global__ __launch_bounds__(256)
void copy_kernel(const float* __restrict__ x, float* __restrict__ out){
  int i = (blockIdx.x*256 + threadIdx.x)*4;
  *(float4*)(out + i) = *(const float4*)(x + i);
}

extern "C" void kernel_launch(void* const* d_in, const int* in_sizes, int n_in,
                              void* d_out, int out_size, void* d_ws, size_t ws_size,
                              hipStream_t stream)
{
  (void)in_sizes; (void)n_in; (void)out_size; (void)ws_size;
  const int* ids      = (const int*)d_in[0];
  // d_in[1] attention_mask: all-False, semantically a no-op -> ignored
  const int* pidx     = (const int*)d_in[2];
  const float* wemb   = (const float*)d_in[3];
  const float* rele   = (const float*)d_in[4];
  const float* rlw    = (const float*)d_in[5];
  const float* rlb    = (const float*)d_in[6];
  const float* Wv     = (const float*)d_in[7];
  const float* Wqk    = (const float*)d_in[8];
  const float* bqk    = (const float*)d_in[9];
  const float* Wo     = (const float*)d_in[10];
  const float* lskip  = (const float*)d_in[11];

  char* wsb = (char*)d_ws;
  float*  x     = (float*) (wsb + 0);           // 12,582,912 B
  ushort* h     = (ushort*)(wsb + 12582912);    //  6,291,456
  ushort* relb  = (ushort*)(wsb + 18874368);    //     98,304
  float*  pos   = (float*) (wsb + 18972672);    //    393,216
  ushort* vg    = (ushort*)(wsb + 19365888);    // 37,748,736
  ushort* qk    = (ushort*)(wsb + 57114624);    // 12,582,912
  float*  cp    = (float*) (wsb + 69697536);    // 12,386,304
  float*  cq    = (float*) (wsb + 82083840);    // 12,386,304
  ushort* ctx   = (ushort*)(wsb + 94470144);    // 18,874,368
  ushort* vt    = (ushort*)(wsb + 113344512);   // 18,874,368
  ushort* ctxln = vt;                           // alias: disjoint live ranges
  ushort* wvb   = (ushort*)(wsb + 132218880);   //  7,077,888
  ushort* wqkb  = (ushort*)(wsb + 139296768);   //  2,359,296
  ushort* wob   = (ushort*)(wsb + 141656064);   //  3,538,944  -> total ~145 MB

  embed_ln_kernel<<<S*B, 256, 0, stream>>>(ids, wemb, x);
  rel_ln_kernel<<<63, 256, 0, stream>>>(rele, rlw, rlb, relb);

  for(int l=0; l<NL; l++){
    const float* Wv_l  = Wv  + (size_t)l * (2*II) * H;
    const float* Wqk_l = Wqk + (size_t)l * (2*H) * H;
    const float* bqk_l = bqk + (size_t)l * (2*H);
    const float* Wo_l  = Wo  + (size_t)l * H * II;
    const float* ls_l  = lskip + (size_t)l * II;

    f2b_kernel<<<(2*II*H)/1024, 256, 0, stream>>>(Wv_l, wvb);
    f2b_kernel<<<(2*H*H)/1024, 256, 0, stream>>>(Wqk_l, wqkb);
    f2b_kernel<<<(H*II)/1024, 256, 0, stream>>>(Wo_l, wob);

    ln_x_kernel<<<S*B, 256, 0, stream>>>(x, h);
    gemm_nt<1><<<dim3((2*II)/64, (S*B)/64), 256, 0, stream>>>(h, wvb, nullptr, vg, S*B, 2*II, H);
    gemm_nt<1><<<dim3((2*H)/64, (S*B)/64), 256, 0, stream>>>(h, wqkb, bqk_l, qk, S*B, 2*H, H);
    gemm_nt<0><<<dim3((2*H)/64, 1), 256, 0, stream>>>(relb, wqkb, bqk_l, pos, 63, 2*H, H);
    cpq_kernel<<<S*B, 256, 0, stream>>>(qk, pos, cp, cq);
    vt_kernel<<<dim3(S/32, NH, B), 256, 0, stream>>>(vg, vt);
    attn_kernel<<<dim3(S/16, NH, B), 256, 0, stream>>>(qk, vt, cp, cq, pidx, ctx);
    glu_ln_kernel<<<S*B, 256, 0, stream>>>(ctx, vg, ls_l, ctxln);
    gemm_nt<2><<<dim3(H/64, (S*B)/64), 256, 0, stream>>>(ctxln, wob, nullptr, x, S*B, H, II);
  }
  copy_kernel<<<(S*B*H)/1024, 256, 0, stream>>>(x, (float*)d_out);
}

// Round 3
// 1612.058 us; speedup vs baseline: 1.5050x; 1.5050x over previous
//
#include <hip/hip_runtime.h>
#include <hip/hip_bf16.h>
#include <math.h>

#define S 512
#define B 8
#define H 768
#define NH 12
#define DH 64
#define DV 192
#define II 2304
#define NL 4
#define SCALE 0.07216878364870322f
#define EPS 1e-7f

typedef __attribute__((ext_vector_type(8))) short short8;
typedef __attribute__((ext_vector_type(4))) float f32x4;

__device__ __forceinline__ float b2f(ushort u){
  union { float f; unsigned int u; } v; v.u = ((unsigned int)u) << 16; return v.f;
}
__device__ __forceinline__ ushort f2b(float f){
  union { float f; unsigned int u; } v; v.f = f;
  unsigned int u = v.u;
  return (ushort)((u + 0x7fffu + ((u >> 16) & 1u)) >> 16);
}
__device__ __forceinline__ float gelu_f(float x){
  return 0.5f * x * (1.0f + erff(x * 0.70710678118654752f));
}
// async global(16B/lane) -> LDS (wave-uniform base + lane*16)
__device__ __forceinline__ void async_copy16(const ushort* g, ushort* l){
  __builtin_amdgcn_global_load_lds(
      (const __attribute__((address_space(1))) void*)g,
      (__attribute__((address_space(3))) void*)l, 16, 0, 0);
}

// ---- block-wide sum of two floats across 256 threads (4 waves) ----
__device__ __forceinline__ void block_sum2(float& s, float& s2, float* red, int t){
  #pragma unroll
  for(int off=32; off>=1; off>>=1){ s += __shfl_xor(s, off); s2 += __shfl_xor(s2, off); }
  int w = t >> 6;
  if((t & 63) == 0){ red[w] = s; red[4 + w] = s2; }
  __syncthreads();
  s  = red[0] + red[1] + red[2] + red[3];
  s2 = red[4] + red[5] + red[6] + red[7];
}

// ---- f32 -> bf16 bulk convert (n divisible by 1024) ----
__global__ __launch_bounds__(256)
void f2b_kernel(const float* __restrict__ in, ushort* __restrict__ out){
  int i = (blockIdx.x * 256 + threadIdx.x) * 4;
  float4 v = *(const float4*)(in + i);
  __attribute__((aligned(8))) ushort tmp[4] = { f2b(v.x), f2b(v.y), f2b(v.z), f2b(v.w) };
  *(uint2*)(out + i) = *(const uint2*)tmp;
}

// ---- x = LN(word_emb[ids])  (f32 in, f32 out) ----
__global__ __launch_bounds__(256)
void embed_ln_kernel(const int* __restrict__ ids, const float* __restrict__ wemb,
                     float* __restrict__ x)
{
  __shared__ float red[8];
  const int sb = blockIdx.x, t = threadIdx.x;
  const float* row = wemb + (size_t)ids[sb] * H;
  float v0 = row[t], v1 = row[t+256], v2 = row[t+512];
  float s = v0+v1+v2, s2 = v0*v0+v1*v1+v2*v2;
  block_sum2(s, s2, red, t);
  float mean = s * (1.0f/H);
  float rstd = rsqrtf(s2*(1.0f/H) - mean*mean + EPS);
  float* xo = x + (size_t)sb * H;
  xo[t]     = (v0-mean)*rstd;
  xo[t+256] = (v1-mean)*rstd;
  xo[t+512] = (v2-mean)*rstd;
}

// ---- relb = LN(rel_emb)*w + b  (f32 in, bf16 out) ----
__global__ __launch_bounds__(256)
void rel_ln_kernel(const float* __restrict__ rel_emb, const float* __restrict__ w,
                   const float* __restrict__ bia, ushort* __restrict__ outb)
{
  __shared__ float red[8];
  const int j = blockIdx.x, t = threadIdx.x;
  const float* row = rel_emb + (size_t)j * H;
  float v0=row[t], v1=row[t+256], v2=row[t+512];
  float s=v0+v1+v2, s2=v0*v0+v1*v1+v2*v2;
  block_sum2(s,s2,red,t);
  float mean = s*(1.0f/H);
  float rstd = rsqrtf(s2*(1.0f/H)-mean*mean+EPS);
  ushort* o = outb + (size_t)j*H;
  o[t]     = f2b((v0-mean)*rstd * w[t]     + bia[t]);
  o[t+256] = f2b((v1-mean)*rstd * w[t+256] + bia[t+256]);
  o[t+512] = f2b((v2-mean)*rstd * w[t+512] + bia[t+512]);
}

// ---- h = LN(x)  (bf16 out) ----
__global__ __launch_bounds__(256)
void ln_x_kernel(const float* __restrict__ x, ushort* __restrict__ h)
{
  __shared__ float red[8];
  const int sb = blockIdx.x, t = threadIdx.x;
  const float* row = x + (size_t)sb * H;
  float v0 = row[t], v1 = row[t+256], v2 = row[t+512];
  float s = v0+v1+v2, s2 = v0*v0+v1*v1+v2*v2;
  block_sum2(s, s2, red, t);
  float mean = s * (1.0f/H);
  float rstd = rsqrtf(s2*(1.0f/H) - mean*mean + EPS);
  ushort* o = h + (size_t)sb * H;
  o[t]     = f2b((v0-mean)*rstd);
  o[t+256] = f2b((v1-mean)*rstd);
  o[t+512] = f2b((v2-mean)*rstd);
}

// ---- small GEMM (64x64 tile): used only for pos = relb @ Wqk^T + bqk (M=63) ----
__global__ __launch_bounds__(256)
void gemm_nt64(const ushort* __restrict__ A, const ushort* __restrict__ Bw,
               const float* __restrict__ bias, ushort* __restrict__ Cout,
               int M, int N, int K)
{
  __shared__ ushort As[64][40];
  __shared__ ushort Bs[64][40];
  const int n0 = blockIdx.x * 64, m0 = blockIdx.y * 64;
  const int t = threadIdx.x;
  const int lrow = t >> 2, lk = (t & 3) * 8;
  const int lane = t & 63, w = t >> 6, lr = lane & 15, lq = lane >> 4;
  const int wr = (w >> 1) * 32, wc = (w & 1) * 32;
  f32x4 z = {0.f,0.f,0.f,0.f};
  f32x4 acc[2][2] = {{z,z},{z,z}};
  const int arow = m0 + lrow;
  const ushort* aptr = A  + (size_t)arow * K + lk;
  const ushort* bptr = Bw + (size_t)(n0 + lrow) * K + lk;
  for(int k0 = 0; k0 < K; k0 += 32){
    short8 av = {0,0,0,0,0,0,0,0};
    if(arow < M) av = *(const short8*)(aptr + k0);
    short8 bv = *(const short8*)(bptr + k0);
    __syncthreads();
    *(short8*)&As[lrow][lk] = av;
    *(short8*)&Bs[lrow][lk] = bv;
    __syncthreads();
    short8 a0 = *(const short8*)&As[wr + lr][lq * 8];
    short8 a1 = *(const short8*)&As[wr + 16 + lr][lq * 8];
    short8 b0 = *(const short8*)&Bs[wc + lr][lq * 8];
    short8 b1 = *(const short8*)&Bs[wc + 16 + lr][lq * 8];
    acc[0][0] = __builtin_amdgcn_mfma_f32_16x16x32_bf16(a0, b0, acc[0][0], 0,0,0);
    acc[0][1] = __builtin_amdgcn_mfma_f32_16x16x32_bf16(a0, b1, acc[0][1], 0,0,0);
    acc[1][0] = __builtin_amdgcn_mfma_f32_16x16x32_bf16(a1, b0, acc[1][0], 0,0,0);
    acc[1][1] = __builtin_amdgcn_mfma_f32_16x16x32_bf16(a1, b1, acc[1][1], 0,0,0);
  }
  #pragma unroll
  for(int i=0;i<2;i++){
    #pragma unroll
    for(int j=0;j<2;j++){
      #pragma unroll
      for(int r=0;r<4;r++){
        int m = m0 + wr + i*16 + lq*4 + r;
        int n = n0 + wc + j*16 + lr;
        if(m >= M) continue;
        float v = acc[i][j][r];
        if(bias) v += bias[n];
        Cout[(size_t)m*N + n] = f2b(v);
      }
    }
  }
}

// ---- main GEMM (m97 structure): 128x128 tile, global_load_lds(16B) staging ----
// C[m][n] = sum_k A[m][k]*Bw[n][k] (+bias[n]); M,N multiples of 128.
// OUT_MODE: 0 = f32 store, 1 = bf16 store, 2 = f32 accumulate (+=)
template<int OUT_MODE>
__global__ __launch_bounds__(256)
void gemm128(const ushort* __restrict__ A, const ushort* __restrict__ Bw,
             const float* __restrict__ bias, void* __restrict__ Cout,
             int M, int N, int K)
{
  __shared__ ushort As[128*32];
  __shared__ ushort Bs[128*32];
  const int t = threadIdx.x, w = t>>6, lane = t&63, lr = lane&15, lq = lane>>4;
  const int m0 = blockIdx.y*128, n0 = blockIdx.x*128;
  const int wr = (w>>1)*64, wc = (w&1)*64;
  // staging map: instr (w,j): LDS rows (w*2+j)*16..+16; lane i -> row+=i>>2, k=(i&3)*8
  const int srow = (w*2)*16 + (lane>>2);
  const int sk = (lane&3)*8;
  const ushort* aG = A  + (size_t)(m0+srow)*K + sk;
  const ushort* bG = Bw + (size_t)(n0+srow)*K + sk;
  ushort* aL0 = As + (w*2)*512;
  ushort* aL1 = As + (w*2+1)*512;
  ushort* bL0 = Bs + (w*2)*512;
  ushort* bL1 = Bs + (w*2+1)*512;
  f32x4 z = {0.f,0.f,0.f,0.f};
  f32x4 acc[4][4] = {{z,z,z,z},{z,z,z,z},{z,z,z,z},{z,z,z,z}};
  for(int k0 = 0; k0 < K; k0 += 32){
    __syncthreads();
    async_copy16(aG + k0,                 aL0);
    async_copy16(aG + k0 + (size_t)16*K,  aL1);
    async_copy16(bG + k0,                 bL0);
    async_copy16(bG + k0 + (size_t)16*K,  bL1);
    __syncthreads();
    short8 af[4], bf[4];
    #pragma unroll
    for(int i=0;i<4;i++) af[i] = *(const short8*)&As[(wr + i*16 + lr)*32 + lq*8];
    #pragma unroll
    for(int j=0;j<4;j++) bf[j] = *(const short8*)&Bs[(wc + j*16 + lr)*32 + lq*8];
    #pragma unroll
    for(int i=0;i<4;i++)
      #pragma unroll
      for(int j=0;j<4;j++)
        acc[i][j] = __builtin_amdgcn_mfma_f32_16x16x32_bf16(af[i], bf[j], acc[i][j], 0,0,0);
  }
  #pragma unroll
  for(int i=0;i<4;i++){
    #pragma unroll
    for(int j=0;j<4;j++){
      #pragma unroll
      for(int r=0;r<4;r++){
        int m = m0 + wr + i*16 + lq*4 + r;
        int n = n0 + wc + j*16 + lr;
        float v = acc[i][j][r];
        if(bias) v += bias[n];
        if(OUT_MODE == 0)      ((float*) Cout)[(size_t)m*N + n] = v;
        else if(OUT_MODE == 1) ((ushort*)Cout)[(size_t)m*N + n] = f2b(v);
        else                   ((float*) Cout)[(size_t)m*N + n] += v;
      }
    }
  }
}

// ---- cp/cq via MFMA: cp[q,b,h,j]=q·kpos[j,h], cq[k,b,h,j]=k·qpos[j,h] ----
// grid (S/64, B*NH, 2); block 256. posb: bf16 [64 rows][1536] (row 63 = scratch garbage,
// finite; col 63 of output discarded).
__global__ __launch_bounds__(256)
void cpq_mfma_kernel(const ushort* __restrict__ qk, const ushort* __restrict__ posb,
                     float* __restrict__ cp, float* __restrict__ cq)
{
  const int mt = blockIdx.x;
  const int b = blockIdx.y >> 4, hh = blockIdx.y & 15;   // gridDim.y = B*16? NO
  // (set gridDim.y = B*NH = 96; decode below instead)
  const int bh = blockIdx.y;
  const int bb = bh / NH, h = bh - bb*NH;
  const int which = blockIdx.z;
  const int t = threadIdx.x, w = t>>6, lane = t&63, lr = lane&15, lq = lane>>4;
  (void)b; (void)hh;
  const int q0 = mt*64 + w*16;
  const ushort* abase = qk + ((size_t)(q0+lr)*B + bb)*1536 + which*768 + h*64;
  short8 a0 = *(const short8*)(abase + lq*8);
  short8 a1 = *(const short8*)(abase + 32 + lq*8);
  const ushort* bbase = posb + (which ? 0 : 768) + h*64;
  f32x4 z = {0.f,0.f,0.f,0.f};
  f32x4 acc[4] = {z,z,z,z};
  #pragma unroll
  for(int jt=0; jt<4; jt++){
    const ushort* bp = bbase + (size_t)(jt*16+lr)*1536;
    short8 b0 = *(const short8*)(bp + lq*8);
    short8 b1 = *(const short8*)(bp + 32 + lq*8);
    acc[jt] = __builtin_amdgcn_mfma_f32_16x16x32_bf16(a0, b0, acc[jt], 0,0,0);
    acc[jt] = __builtin_amdgcn_mfma_f32_16x16x32_bf16(a1, b1, acc[jt], 0,0,0);
  }
  float* outp = which ? cq : cp;
  #pragma unroll
  for(int jt=0; jt<4; jt++){
    int j = jt*16 + lr;
    if(j >= 63) continue;
    #pragma unroll
    for(int r=0;r<4;r++){
      int q = q0 + lq*4 + r;
      outp[(((size_t)q*B + bb)*NH + h)*63 + j] = acc[jt][r];
    }
  }
}

// ---- Vt[b][h][v][s] = value[s][b][h*DV+v]  (bf16) ----
__global__ __launch_bounds__(256)
void vt_kernel(const ushort* __restrict__ vg, ushort* __restrict__ vt)
{
  const int st = blockIdx.x, hh = blockIdx.y, b = blockIdx.z;
  __shared__ ushort tile[32][200];
  const int t = threadIdx.x;
  {
    int sl = t >> 3, v0 = (t & 7) * 24;
    const ushort* src = vg + ((size_t)((st*32 + sl)*B + b))*(2*II) + hh*DV + v0;
    *(short8*)&tile[sl][v0]      = *(const short8*)(src);
    *(short8*)&tile[sl][v0 + 8]  = *(const short8*)(src + 8);
    *(short8*)&tile[sl][v0 + 16] = *(const short8*)(src + 16);
  }
  __syncthreads();
  if(t < DV){
    __attribute__((aligned(16))) ushort tmp[32];
    #pragma unroll
    for(int s2=0;s2<32;s2++) tmp[s2] = tile[s2][t];
    ushort* dst = vt + (((size_t)(b*NH + hh))*DV + t)*S + st*32;
    #pragma unroll
    for(int c=0;c<32;c+=8) *(short8*)(dst + c) = *(const short8*)&tmp[c];
  }
}

// ---- fused attention: scores(MFMA)+rel-pos gathers+softmax+PV(MFMA) ----
__global__ __launch_bounds__(256)
void attn_kernel(const ushort* __restrict__ qk, const ushort* __restrict__ vt,
                 const float* __restrict__ cp, const float* __restrict__ cq,
                 const int* __restrict__ pidx, ushort* __restrict__ ctx)
{
  const int qt = blockIdx.x, hh = blockIdx.y, b = blockIdx.z;
  __shared__ ushort Qs[16][72];
  __shared__ ushort Ps[16][520];
  __shared__ float cps[16][64];
  __shared__ float redm[4][16];
  __shared__ float reds[4][16];
  __shared__ float rowinv[16];
  const int t = threadIdx.x, w = t>>6, lane = t&63, lr = lane&15, lq = lane>>4;

  {
    int r = t >> 4, d0 = (t & 15) * 4;
    const ushort* src = qk + ((size_t)((qt*16 + r)*B + b))*1536 + hh*DH + d0;
    *(uint2*)&Qs[r][d0] = *(const uint2*)src;
  }
  for(int i=t; i<16*63; i+=256){
    int r = i/63, j = i - r*63;
    cps[r][j] = cp[(((size_t)(qt*16+r)*B + b)*NH + hh)*63 + j];
  }
  __syncthreads();

  float sc[8][4];
  const int kbase = w * 128;
  #pragma unroll
  for(int tile=0; tile<8; tile++){
    const int k0 = kbase + tile*16;
    const ushort* kp = qk + ((size_t)((k0 + lr)*B + b))*1536 + H + hh*DH + lq*8;
    short8 b0 = *(const short8*)kp;
    short8 b1 = *(const short8*)(kp + 32);
    short8 a0 = *(const short8*)&Qs[lr][lq*8];
    short8 a1 = *(const short8*)&Qs[lr][32 + lq*8];
    f32x4 acc = {0.f,0.f,0.f,0.f};
    acc = __builtin_amdgcn_mfma_f32_16x16x32_bf16(a0, b0, acc, 0,0,0);
    acc = __builtin_amdgcn_mfma_f32_16x16x32_bf16(a1, b1, acc, 0,0,0);
    const int kcol = k0 + lr;
    #pragma unroll
    for(int r=0;r<4;r++){
      int ql = lq*4 + r;
      int pi = pidx[(qt*16+ql)*S + kcol];
      sc[tile][r] = (acc[r] + cps[ql][pi]
                     + cq[(((size_t)kcol*B + b)*NH + hh)*63 + pi]) * SCALE;
    }
  }

  float gm[4], gs[4];
  #pragma unroll
  for(int r=0;r<4;r++){
    float m = sc[0][r];
    #pragma unroll
    for(int tile=1;tile<8;tile++) m = fmaxf(m, sc[tile][r]);
    #pragma unroll
    for(int off=1; off<16; off<<=1) m = fmaxf(m, __shfl_xor(m, off));
    if(lr==0) redm[w][lq*4+r] = m;
  }
  __syncthreads();
  #pragma unroll
  for(int r=0;r<4;r++){
    int row = lq*4+r;
    gm[r] = fmaxf(fmaxf(redm[0][row],redm[1][row]),fmaxf(redm[2][row],redm[3][row]));
  }
  #pragma unroll
  for(int r=0;r<4;r++){
    float s = 0.f;
    #pragma unroll
    for(int tile=0;tile<8;tile++){ float e = __expf(sc[tile][r]-gm[r]); sc[tile][r]=e; s+=e; }
    #pragma unroll
    for(int off=1; off<16; off<<=1) s += __shfl_xor(s, off);
    if(lr==0) reds[w][lq*4+r] = s;
  }
  __syncthreads();
  #pragma unroll
  for(int r=0;r<4;r++){
    int row = lq*4+r;
    gs[r] = reds[0][row]+reds[1][row]+reds[2][row]+reds[3][row];
    if(w==0 && lr==0) rowinv[row] = 1.0f/gs[r];
  }
  #pragma unroll
  for(int tile=0;tile<8;tile++){
    #pragma unroll
    for(int r=0;r<4;r++) Ps[lq*4+r][kbase + tile*16 + lr] = f2b(sc[tile][r]);
  }
  __syncthreads();

  f32x4 z = {0.f,0.f,0.f,0.f};
  f32x4 acc2[3] = {z,z,z};
  const ushort* vbase = vt + ((size_t)(b*NH + hh))*DV*S;
  for(int kk=0; kk<S; kk+=32){
    short8 a = *(const short8*)&Ps[lr][kk + lq*8];
    #pragma unroll
    for(int ti=0; ti<3; ti++){
      const int v0 = (w*3 + ti)*16;
      short8 bv = *(const short8*)(vbase + (size_t)(v0 + lr)*S + kk + lq*8);
      acc2[ti] = __builtin_amdgcn_mfma_f32_16x16x32_bf16(a, bv, acc2[ti], 0,0,0);
    }
  }
  #pragma unroll
  for(int ti=0; ti<3; ti++){
    const int v0 = (w*3 + ti)*16;
    #pragma unroll
    for(int r=0;r<4;r++){
      int ql = lq*4 + r;
      float val = acc2[ti][r] * rowinv[ql];
      ctx[((size_t)((qt*16+ql)*B + b))*II + hh*DV + v0 + lr] = f2b(val);
    }
  }
}

// ---- ctx2 = LN( (ctx + sigmoid(lskip)*gelu(value)) * gelu(gate) )  (bf16) ----
__global__ __launch_bounds__(256)
void glu_ln_kernel(const ushort* __restrict__ ctx, const ushort* __restrict__ vg,
                   const float* __restrict__ ls, ushort* __restrict__ outb)
{
  __shared__ float red[8];
  const int sb = blockIdx.x, t = threadIdx.x;
  const ushort* crow = ctx + (size_t)sb*II;
  const ushort* vrow = vg + (size_t)sb*2*II;
  float c[9]; float s=0.f, s2=0.f;
  #pragma unroll
  for(int i=0;i<9;i++){
    int idx = t + i*256;
    float cv  = b2f(crow[idx]);
    float val = b2f(vrow[idx]);
    float gt  = b2f(vrow[II + idx]);
    float sk  = 1.0f/(1.0f + __expf(-ls[idx]));
    cv = (cv + sk*gelu_f(val)) * gelu_f(gt);
    c[i]=cv; s+=cv; s2+=cv*cv;
  }
  block_sum2(s,s2,red,t);
  float mean = s*(1.0f/II);
  float rstd = rsqrtf(s2*(1.0f/II)-mean*mean+EPS);
  ushort* o = outb + (size_t)sb*II;
  #pragma unroll
  for(int i=0;i<9;i++) o[t+i*256] = f2b((c[i]-mean)*rstd);
}

// ---- final copy x(f32) -> out(f32) ----
__global__ __launch_bounds__(256)
void copy_kernel(const float* __restrict__ x, float* __restrict__ out){
  int i = (blockIdx.x*256 + threadIdx.x)*4;
  *(float4*)(out + i) = *(const float4*)(x + i);
}

extern "C" void kernel_launch(void* const* d_in, const int* in_sizes, int n_in,
                              void* d_out, int out_size, void* d_ws, size_t ws_size,
                              hipStream_t stream)
{
  (void)in_sizes; (void)n_in; (void)out_size; (void)ws_size;
  const int* ids      = (const int*)d_in[0];
  const int* pidx     = (const int*)d_in[2];
  const float* wemb   = (const float*)d_in[3];
  const float* rele   = (const float*)d_in[4];
  const float* rlw    = (const float*)d_in[5];
  const float* rlb    = (const float*)d_in[6];
  const float* Wv     = (const float*)d_in[7];
  const float* Wqk    = (const float*)d_in[8];
  const float* bqk    = (const float*)d_in[9];
  const float* Wo     = (const float*)d_in[10];
  const float* lskip  = (const float*)d_in[11];

  char* wsb = (char*)d_ws;
  float*  x     = (float*) (wsb + 0);           // 12,582,912 B
  ushort* h     = (ushort*)(wsb + 12582912);    //  6,291,456
  ushort* relb  = (ushort*)(wsb + 18874368);    //     98,304
  ushort* posb  = (ushort*)(wsb + 18972672);    //    196,608 (64 rows x 1536 bf16)
  ushort* vg    = (ushort*)(wsb + 19169280);    // 37,748,736
  ushort* qk    = (ushort*)(wsb + 56918016);    // 12,582,912
  float*  cp    = (float*) (wsb + 69500928);    // 12,386,304
  float*  cq    = (float*) (wsb + 81887232);    // 12,386,304
  ushort* ctx   = (ushort*)(wsb + 94273536);    // 18,874,368
  ushort* vt    = (ushort*)(wsb + 113147904);   // 18,874,368
  ushort* ctxln = vt;                           // alias: disjoint live ranges
  ushort* wvb   = (ushort*)(wsb + 132022272);   //  7,077,888
  ushort* wqkb  = (ushort*)(wsb + 139100160);   //  2,359,296
  ushort* wob   = (ushort*)(wsb + 141459456);   //  3,538,944  -> total ~145 MB

  embed_ln_kernel<<<S*B, 256, 0, stream>>>(ids, wemb, x);
  rel_ln_kernel<<<63, 256, 0, stream>>>(rele, rlw, rlb, relb);

  for(int l=0; l<NL; l++){
    const float* Wv_l  = Wv  + (size_t)l * (2*II) * H;
    const float* Wqk_l = Wqk + (size_t)l * (2*H) * H;
    const float* bqk_l = bqk + (size_t)l * (2*H);
    const float* Wo_l  = Wo  + (size_t)l * H * II;
    const float* ls_l  = lskip + (size_t)l * II;

    f2b_kernel<<<(2*II*H)/1024, 256, 0, stream>>>(Wv_l, wvb);
    f2b_kernel<<<(2*H*H)/1024, 256, 0, stream>>>(Wqk_l, wqkb);
    f2b_kernel<<<(H*II)/1024, 256, 0, stream>>>(Wo_l, wob);

    ln_x_kernel<<<S*B, 256, 0, stream>>>(x, h);
    gemm128<1><<<dim3((2*II)/128, (S*B)/128), 256, 0, stream>>>(h, wvb, nullptr, vg, S*B, 2*II, H);
    gemm128<1><<<dim3((2*H)/128, (S*B)/128), 256, 0, stream>>>(h, wqkb, bqk_l, qk, S*B, 2*H, H);
    gemm_nt64<<<dim3((2*H)/64, 1), 256, 0, stream>>>(relb, wqkb, bqk_l, posb, 63, 2*H, H);
    cpq_mfma_kernel<<<dim3(S/64, B*NH, 2), 256, 0, stream>>>(qk, posb, cp, cq);
    vt_kernel<<<dim3(S/32, NH, B), 256, 0, stream>>>(vg, vt);
    attn_kernel<<<dim3(S/16, NH, B), 256, 0, stream>>>(qk, vt, cp, cq, pidx, ctx);
    glu_ln_kernel<<<S*B, 256, 0, stream>>>(ctx, vg, ls_l, ctxln);
    gemm128<2><<<dim3(H/128, (S*B)/128), 256, 0, stream>>>(ctxln, wob, nullptr, x, S*B, H, II);
  }
  copy_kernel<<<(S*B*H)/1024, 256, 0, stream>>>(x, (float*)d_out);
}

// Round 4
// 1462.384 us; speedup vs baseline: 1.6590x; 1.1023x over previous
//
#include <hip/hip_runtime.h>
#include <hip/hip_bf16.h>
#include <math.h>

#define S 512
#define B 8
#define H 768
#define NH 12
#define DH 64
#define DV 192
#define II 2304
#define NL 4
#define SCALE 0.07216878364870322f
#define EPS 1e-7f

typedef __attribute__((ext_vector_type(8))) short short8;
typedef __attribute__((ext_vector_type(4))) float f32x4;

__device__ __forceinline__ float b2f(ushort u){
  union { float f; unsigned int u; } v; v.u = ((unsigned int)u) << 16; return v.f;
}
__device__ __forceinline__ ushort f2b(float f){
  union { float f; unsigned int u; } v; v.f = f;
  unsigned int u = v.u;
  return (ushort)((u + 0x7fffu + ((u >> 16) & 1u)) >> 16);
}
__device__ __forceinline__ float gelu_f(float x){
  return 0.5f * x * (1.0f + erff(x * 0.70710678118654752f));
}
// async global(16B/lane) -> LDS (wave-uniform base + lane*16)
__device__ __forceinline__ void async_copy16(const ushort* g, ushort* l){
  __builtin_amdgcn_global_load_lds(
      (const __attribute__((address_space(1))) void*)g,
      (__attribute__((address_space(3))) void*)l, 16, 0, 0);
}

// ---- block-wide sum of two floats across 256 threads (4 waves) ----
__device__ __forceinline__ void block_sum2(float& s, float& s2, float* red, int t){
  #pragma unroll
  for(int off=32; off>=1; off>>=1){ s += __shfl_xor(s, off); s2 += __shfl_xor(s2, off); }
  int w = t >> 6;
  if((t & 63) == 0){ red[w] = s; red[4 + w] = s2; }
  __syncthreads();
  s  = red[0] + red[1] + red[2] + red[3];
  s2 = red[4] + red[5] + red[6] + red[7];
}

// ---- f32 -> bf16 bulk convert (n divisible by 1024) ----
__global__ __launch_bounds__(256)
void f2b_kernel(const float* __restrict__ in, ushort* __restrict__ out){
  int i = (blockIdx.x * 256 + threadIdx.x) * 4;
  float4 v = *(const float4*)(in + i);
  __attribute__((aligned(8))) ushort tmp[4] = { f2b(v.x), f2b(v.y), f2b(v.z), f2b(v.w) };
  *(uint2*)(out + i) = *(const uint2*)tmp;
}

// ---- x = LN(word_emb[ids])  (f32 in, f32 out) ----
__global__ __launch_bounds__(256)
void embed_ln_kernel(const int* __restrict__ ids, const float* __restrict__ wemb,
                     float* __restrict__ x)
{
  __shared__ float red[8];
  const int sb = blockIdx.x, t = threadIdx.x;
  const float* row = wemb + (size_t)ids[sb] * H;
  float v0 = row[t], v1 = row[t+256], v2 = row[t+512];
  float s = v0+v1+v2, s2 = v0*v0+v1*v1+v2*v2;
  block_sum2(s, s2, red, t);
  float mean = s * (1.0f/H);
  float rstd = rsqrtf(s2*(1.0f/H) - mean*mean + EPS);
  float* xo = x + (size_t)sb * H;
  xo[t]     = (v0-mean)*rstd;
  xo[t+256] = (v1-mean)*rstd;
  xo[t+512] = (v2-mean)*rstd;
}

// ---- relb = LN(rel_emb)*w + b  (f32 in, bf16 out) ----
__global__ __launch_bounds__(256)
void rel_ln_kernel(const float* __restrict__ rel_emb, const float* __restrict__ w,
                   const float* __restrict__ bia, ushort* __restrict__ outb)
{
  __shared__ float red[8];
  const int j = blockIdx.x, t = threadIdx.x;
  const float* row = rel_emb + (size_t)j * H;
  float v0=row[t], v1=row[t+256], v2=row[t+512];
  float s=v0+v1+v2, s2=v0*v0+v1*v1+v2*v2;
  block_sum2(s,s2,red,t);
  float mean = s*(1.0f/H);
  float rstd = rsqrtf(s2*(1.0f/H)-mean*mean+EPS);
  ushort* o = outb + (size_t)j*H;
  o[t]     = f2b((v0-mean)*rstd * w[t]     + bia[t]);
  o[t+256] = f2b((v1-mean)*rstd * w[t+256] + bia[t+256]);
  o[t+512] = f2b((v2-mean)*rstd * w[t+512] + bia[t+512]);
}

// ---- h = LN(x)  (bf16 out) ----
__global__ __launch_bounds__(256)
void ln_x_kernel(const float* __restrict__ x, ushort* __restrict__ h)
{
  __shared__ float red[8];
  const int sb = blockIdx.x, t = threadIdx.x;
  const float* row = x + (size_t)sb * H;
  float v0 = row[t], v1 = row[t+256], v2 = row[t+512];
  float s = v0+v1+v2, s2 = v0*v0+v1*v1+v2*v2;
  block_sum2(s, s2, red, t);
  float mean = s * (1.0f/H);
  float rstd = rsqrtf(s2*(1.0f/H) - mean*mean + EPS);
  ushort* o = h + (size_t)sb * H;
  o[t]     = f2b((v0-mean)*rstd);
  o[t+256] = f2b((v1-mean)*rstd);
  o[t+512] = f2b((v2-mean)*rstd);
}

// ---- small GEMM (64x64 tile): used only for pos = relb @ Wqk^T + bqk (M=63) ----
__global__ __launch_bounds__(256)
void gemm_nt64(const ushort* __restrict__ A, const ushort* __restrict__ Bw,
               const float* __restrict__ bias, ushort* __restrict__ Cout,
               int M, int N, int K)
{
  __shared__ ushort As[64][40];
  __shared__ ushort Bs[64][40];
  const int n0 = blockIdx.x * 64, m0 = blockIdx.y * 64;
  const int t = threadIdx.x;
  const int lrow = t >> 2, lk = (t & 3) * 8;
  const int lane = t & 63, w = t >> 6, lr = lane & 15, lq = lane >> 4;
  const int wr = (w >> 1) * 32, wc = (w & 1) * 32;
  f32x4 z = {0.f,0.f,0.f,0.f};
  f32x4 acc[2][2] = {{z,z},{z,z}};
  const int arow = m0 + lrow;
  const ushort* aptr = A  + (size_t)arow * K + lk;
  const ushort* bptr = Bw + (size_t)(n0 + lrow) * K + lk;
  for(int k0 = 0; k0 < K; k0 += 32){
    short8 av = {0,0,0,0,0,0,0,0};
    if(arow < M) av = *(const short8*)(aptr + k0);
    short8 bv = *(const short8*)(bptr + k0);
    __syncthreads();
    *(short8*)&As[lrow][lk] = av;
    *(short8*)&Bs[lrow][lk] = bv;
    __syncthreads();
    short8 a0 = *(const short8*)&As[wr + lr][lq * 8];
    short8 a1 = *(const short8*)&As[wr + 16 + lr][lq * 8];
    short8 b0 = *(const short8*)&Bs[wc + lr][lq * 8];
    short8 b1 = *(const short8*)&Bs[wc + 16 + lr][lq * 8];
    acc[0][0] = __builtin_amdgcn_mfma_f32_16x16x32_bf16(a0, b0, acc[0][0], 0,0,0);
    acc[0][1] = __builtin_amdgcn_mfma_f32_16x16x32_bf16(a0, b1, acc[0][1], 0,0,0);
    acc[1][0] = __builtin_amdgcn_mfma_f32_16x16x32_bf16(a1, b0, acc[1][0], 0,0,0);
    acc[1][1] = __builtin_amdgcn_mfma_f32_16x16x32_bf16(a1, b1, acc[1][1], 0,0,0);
  }
  #pragma unroll
  for(int i=0;i<2;i++){
    #pragma unroll
    for(int j=0;j<2;j++){
      #pragma unroll
      for(int r=0;r<4;r++){
        int m = m0 + wr + i*16 + lq*4 + r;
        int n = n0 + wc + j*16 + lr;
        if(m >= M) continue;
        float v = acc[i][j][r];
        if(bias) v += bias[n];
        Cout[(size_t)m*N + n] = f2b(v);
      }
    }
  }
}

// ---- main GEMM (m97 structure): 128x128 tile, global_load_lds(16B) staging ----
// C[m][n] = sum_k A[m][k]*Bw[n][k] (+bias[n]); M,N multiples of 128.
// OUT_MODE: 0 = f32 store, 1 = bf16 store, 2 = f32 accumulate (+=)
template<int OUT_MODE>
__global__ __launch_bounds__(256)
void gemm128(const ushort* __restrict__ A, const ushort* __restrict__ Bw,
             const float* __restrict__ bias, void* __restrict__ Cout,
             int M, int N, int K)
{
  __shared__ ushort As[128*32];
  __shared__ ushort Bs[128*32];
  const int t = threadIdx.x, w = t>>6, lane = t&63, lr = lane&15, lq = lane>>4;
  const int m0 = blockIdx.y*128, n0 = blockIdx.x*128;
  const int wr = (w>>1)*64, wc = (w&1)*64;
  const int srow = (w*2)*16 + (lane>>2);
  const int sk = (lane&3)*8;
  const ushort* aG = A  + (size_t)(m0+srow)*K + sk;
  const ushort* bG = Bw + (size_t)(n0+srow)*K + sk;
  ushort* aL0 = As + (w*2)*512;
  ushort* aL1 = As + (w*2+1)*512;
  ushort* bL0 = Bs + (w*2)*512;
  ushort* bL1 = Bs + (w*2+1)*512;
  f32x4 z = {0.f,0.f,0.f,0.f};
  f32x4 acc[4][4] = {{z,z,z,z},{z,z,z,z},{z,z,z,z},{z,z,z,z}};
  for(int k0 = 0; k0 < K; k0 += 32){
    __syncthreads();
    async_copy16(aG + k0,                 aL0);
    async_copy16(aG + k0 + (size_t)16*K,  aL1);
    async_copy16(bG + k0,                 bL0);
    async_copy16(bG + k0 + (size_t)16*K,  bL1);
    __syncthreads();
    short8 af[4], bf[4];
    #pragma unroll
    for(int i=0;i<4;i++) af[i] = *(const short8*)&As[(wr + i*16 + lr)*32 + lq*8];
    #pragma unroll
    for(int j=0;j<4;j++) bf[j] = *(const short8*)&Bs[(wc + j*16 + lr)*32 + lq*8];
    #pragma unroll
    for(int i=0;i<4;i++)
      #pragma unroll
      for(int j=0;j<4;j++)
        acc[i][j] = __builtin_amdgcn_mfma_f32_16x16x32_bf16(af[i], bf[j], acc[i][j], 0,0,0);
  }
  #pragma unroll
  for(int i=0;i<4;i++){
    #pragma unroll
    for(int j=0;j<4;j++){
      #pragma unroll
      for(int r=0;r<4;r++){
        int m = m0 + wr + i*16 + lq*4 + r;
        int n = n0 + wc + j*16 + lr;
        float v = acc[i][j][r];
        if(bias) v += bias[n];
        if(OUT_MODE == 0)      ((float*) Cout)[(size_t)m*N + n] = v;
        else if(OUT_MODE == 1) ((ushort*)Cout)[(size_t)m*N + n] = f2b(v);
        else                   ((float*) Cout)[(size_t)m*N + n] += v;
      }
    }
  }
}

// ---- cp/cq transposed via MFMA ----
// cpT[b][h][j][q] = q4(q,b,h)·kpos(j,h);  cqT[b][h][j][k] = k4(k,b,h)·qpos(j,h)
// Output bf16, layout [(b*NH+h)*64 + j]*512 + s  (s contiguous -> coalesced gather in attn).
// grid (S/128, B*NH, 2); block 256. j-row 63 is garbage (never gathered: pidx in [0,62]).
__global__ __launch_bounds__(256)
void cpq_mfma2_kernel(const ushort* __restrict__ qk, const ushort* __restrict__ posb,
                      ushort* __restrict__ cpT, ushort* __restrict__ cqT)
{
  const int kc = blockIdx.x;
  const int bh = blockIdx.y;
  const int bb = bh / NH, h = bh - bb*NH;
  const int which = blockIdx.z;
  const int t = threadIdx.x, w = t>>6, lane = t&63, lr = lane&15, lq = lane>>4;
  // A = pos rows (M = j): which=0 -> k_pos (offset 768); which=1 -> q_pos (offset 0)
  const ushort* ab = posb + (size_t)(w*16 + lr)*1536 + (which ? 0 : 768) + h*64;
  short8 a0 = *(const short8*)(ab + lq*8);
  short8 a1 = *(const short8*)(ab + 32 + lq*8);
  f32x4 z = {0.f,0.f,0.f,0.f};
  f32x4 acc[8] = {z,z,z,z,z,z,z,z};
  #pragma unroll
  for(int nt=0; nt<8; nt++){
    const int k = kc*128 + nt*16 + lr;
    // B = q/k vectors (N = s): which=0 -> q (offset 0); which=1 -> k (offset 768)
    const ushort* bp = qk + ((size_t)k*B + bb)*1536 + (which ? 768 : 0) + h*64;
    short8 b0 = *(const short8*)(bp + lq*8);
    short8 b1 = *(const short8*)(bp + 32 + lq*8);
    acc[nt] = __builtin_amdgcn_mfma_f32_16x16x32_bf16(a0, b0, acc[nt], 0,0,0);
    acc[nt] = __builtin_amdgcn_mfma_f32_16x16x32_bf16(a1, b1, acc[nt], 0,0,0);
  }
  ushort* outp = which ? cqT : cpT;
  #pragma unroll
  for(int nt=0; nt<8; nt++){
    #pragma unroll
    for(int r=0;r<4;r++){
      int j = w*16 + lq*4 + r;
      int k = kc*128 + nt*16 + lr;
      outp[((size_t)bh*64 + j)*512 + k] = f2b(acc[nt][r]);
    }
  }
}

// ---- Vt[b][h][v][s] = value[s][b][h*DV+v]  (bf16) ----
__global__ __launch_bounds__(256)
void vt_kernel(const ushort* __restrict__ vg, ushort* __restrict__ vt)
{
  const int st = blockIdx.x, hh = blockIdx.y, b = blockIdx.z;
  __shared__ ushort tile[32][200];
  const int t = threadIdx.x;
  {
    int sl = t >> 3, v0 = (t & 7) * 24;
    const ushort* src = vg + ((size_t)((st*32 + sl)*B + b))*(2*II) + hh*DV + v0;
    *(short8*)&tile[sl][v0]      = *(const short8*)(src);
    *(short8*)&tile[sl][v0 + 8]  = *(const short8*)(src + 8);
    *(short8*)&tile[sl][v0 + 16] = *(const short8*)(src + 16);
  }
  __syncthreads();
  if(t < DV){
    __attribute__((aligned(16))) ushort tmp[32];
    #pragma unroll
    for(int s2=0;s2<32;s2++) tmp[s2] = tile[s2][t];
    ushort* dst = vt + (((size_t)(b*NH + hh))*DV + t)*S + st*32;
    #pragma unroll
    for(int c=0;c<32;c+=8) *(short8*)(dst + c) = *(const short8*)&tmp[c];
  }
}

// ---- fused attention: scores(MFMA)+rel-pos gathers+softmax+PV(MFMA) ----
__global__ __launch_bounds__(256)
void attn_kernel(const ushort* __restrict__ qk, const ushort* __restrict__ vt,
                 const ushort* __restrict__ cpT, const ushort* __restrict__ cqT,
                 const int* __restrict__ pidx, ushort* __restrict__ ctx)
{
  const int qt = blockIdx.x, hh = blockIdx.y, b = blockIdx.z;
  const int bh = b*NH + hh;
  __shared__ ushort Qs[16][72];
  __shared__ ushort Ps[16][520];
  __shared__ float cps[16][64];
  __shared__ float redm[4][16];
  __shared__ float reds[4][16];
  __shared__ float rowinv[16];
  const int t = threadIdx.x, w = t>>6, lane = t&63, lr = lane&15, lq = lane>>4;

  {
    int r = t >> 4, d0 = (t & 15) * 4;
    const ushort* src = qk + ((size_t)((qt*16 + r)*B + b))*1536 + hh*DH + d0;
    *(uint2*)&Qs[r][d0] = *(const uint2*)src;
  }
  // stage cp row-block from transposed layout (coalesced: 16 lanes read 16 consecutive q)
  for(int i=t; i<16*64; i+=256){
    int j = i >> 4, r = i & 15;
    cps[r][j] = b2f(cpT[((size_t)bh*64 + j)*512 + qt*16 + r]);
  }
  __syncthreads();

  float sc[8][4];
  const int kbase = w * 128;
  const ushort* cqbase = cqT + (size_t)bh*64*512;
  #pragma unroll
  for(int tile=0; tile<8; tile++){
    const int k0 = kbase + tile*16;
    const ushort* kp = qk + ((size_t)((k0 + lr)*B + b))*1536 + H + hh*DH + lq*8;
    short8 b0 = *(const short8*)kp;
    short8 b1 = *(const short8*)(kp + 32);
    short8 a0 = *(const short8*)&Qs[lr][lq*8];
    short8 a1 = *(const short8*)&Qs[lr][32 + lq*8];
    f32x4 acc = {0.f,0.f,0.f,0.f};
    acc = __builtin_amdgcn_mfma_f32_16x16x32_bf16(a0, b0, acc, 0,0,0);
    acc = __builtin_amdgcn_mfma_f32_16x16x32_bf16(a1, b1, acc, 0,0,0);
    const int kcol = k0 + lr;
    #pragma unroll
    for(int r=0;r<4;r++){
      int ql = lq*4 + r;
      int pi = pidx[(qt*16+ql)*S + kcol];
      sc[tile][r] = (acc[r] + cps[ql][pi]
                     + b2f(cqbase[(size_t)pi*512 + kcol])) * SCALE;
    }
  }

  float gm[4], gs[4];
  #pragma unroll
  for(int r=0;r<4;r++){
    float m = sc[0][r];
    #pragma unroll
    for(int tile=1;tile<8;tile++) m = fmaxf(m, sc[tile][r]);
    #pragma unroll
    for(int off=1; off<16; off<<=1) m = fmaxf(m, __shfl_xor(m, off));
    if(lr==0) redm[w][lq*4+r] = m;
  }
  __syncthreads();
  #pragma unroll
  for(int r=0;r<4;r++){
    int row = lq*4+r;
    gm[r] = fmaxf(fmaxf(redm[0][row],redm[1][row]),fmaxf(redm[2][row],redm[3][row]));
  }
  #pragma unroll
  for(int r=0;r<4;r++){
    float s = 0.f;
    #pragma unroll
    for(int tile=0;tile<8;tile++){ float e = __expf(sc[tile][r]-gm[r]); sc[tile][r]=e; s+=e; }
    #pragma unroll
    for(int off=1; off<16; off<<=1) s += __shfl_xor(s, off);
    if(lr==0) reds[w][lq*4+r] = s;
  }
  __syncthreads();
  #pragma unroll
  for(int r=0;r<4;r++){
    int row = lq*4+r;
    gs[r] = reds[0][row]+reds[1][row]+reds[2][row]+reds[3][row];
    if(w==0 && lr==0) rowinv[row] = 1.0f/gs[r];
  }
  #pragma unroll
  for(int tile=0;tile<8;tile++){
    #pragma unroll
    for(int r=0;r<4;r++) Ps[lq*4+r][kbase + tile*16 + lr] = f2b(sc[tile][r]);
  }
  __syncthreads();

  f32x4 z = {0.f,0.f,0.f,0.f};
  f32x4 acc2[3] = {z,z,z};
  const ushort* vbase = vt + ((size_t)bh)*DV*S;
  for(int kk=0; kk<S; kk+=32){
    short8 a = *(const short8*)&Ps[lr][kk + lq*8];
    #pragma unroll
    for(int ti=0; ti<3; ti++){
      const int v0 = (w*3 + ti)*16;
      short8 bv = *(const short8*)(vbase + (size_t)(v0 + lr)*S + kk + lq*8);
      acc2[ti] = __builtin_amdgcn_mfma_f32_16x16x32_bf16(a, bv, acc2[ti], 0,0,0);
    }
  }
  #pragma unroll
  for(int ti=0; ti<3; ti++){
    const int v0 = (w*3 + ti)*16;
    #pragma unroll
    for(int r=0;r<4;r++){
      int ql = lq*4 + r;
      float val = acc2[ti][r] * rowinv[ql];
      ctx[((size_t)((qt*16+ql)*B + b))*II + hh*DV + v0 + lr] = f2b(val);
    }
  }
}

// ---- ctx2 = LN( (ctx + sigmoid(lskip)*gelu(value)) * gelu(gate) )  (bf16) ----
__global__ __launch_bounds__(256)
void glu_ln_kernel(const ushort* __restrict__ ctx, const ushort* __restrict__ vg,
                   const float* __restrict__ ls, ushort* __restrict__ outb)
{
  __shared__ float red[8];
  const int sb = blockIdx.x, t = threadIdx.x;
  const ushort* crow = ctx + (size_t)sb*II;
  const ushort* vrow = vg + (size_t)sb*2*II;
  float c[9]; float s=0.f, s2=0.f;
  #pragma unroll
  for(int i=0;i<9;i++){
    int idx = t + i*256;
    float cv  = b2f(crow[idx]);
    float val = b2f(vrow[idx]);
    float gt  = b2f(vrow[II + idx]);
    float sk  = 1.0f/(1.0f + __expf(-ls[idx]));
    cv = (cv + sk*gelu_f(val)) * gelu_f(gt);
    c[i]=cv; s+=cv; s2+=cv*cv;
  }
  block_sum2(s,s2,red,t);
  float mean = s*(1.0f/II);
  float rstd = rsqrtf(s2*(1.0f/II)-mean*mean+EPS);
  ushort* o = outb + (size_t)sb*II;
  #pragma unroll
  for(int i=0;i<9;i++) o[t+i*256] = f2b((c[i]-mean)*rstd);
}

// ---- final copy x(f32) -> out(f32) ----
__global__ __launch_bounds__(256)
void copy_kernel(const float* __restrict__ x, float* __restrict__ out){
  int i = (blockIdx.x*256 + threadIdx.x)*4;
  *(float4*)(out + i) = *(const float4*)(x + i);
}

extern "C" void kernel_launch(void* const* d_in, const int* in_sizes, int n_in,
                              void* d_out, int out_size, void* d_ws, size_t ws_size,
                              hipStream_t stream)
{
  (void)in_sizes; (void)n_in; (void)out_size; (void)ws_size;
  const int* ids      = (const int*)d_in[0];
  const int* pidx     = (const int*)d_in[2];
  const float* wemb   = (const float*)d_in[3];
  const float* rele   = (const float*)d_in[4];
  const float* rlw    = (const float*)d_in[5];
  const float* rlb    = (const float*)d_in[6];
  const float* Wv     = (const float*)d_in[7];
  const float* Wqk    = (const float*)d_in[8];
  const float* bqk    = (const float*)d_in[9];
  const float* Wo     = (const float*)d_in[10];
  const float* lskip  = (const float*)d_in[11];

  char* wsb = (char*)d_ws;
  float*  x     = (float*) (wsb + 0);           // 12,582,912 B
  ushort* h     = (ushort*)(wsb + 12582912);    //  6,291,456
  ushort* relb  = (ushort*)(wsb + 18874368);    //     98,304
  ushort* posb  = (ushort*)(wsb + 18972672);    //    196,608 (64 rows x 1536 bf16)
  ushort* vg    = (ushort*)(wsb + 19169280);    // 37,748,736
  ushort* qk    = (ushort*)(wsb + 56918016);    // 12,582,912
  ushort* cpT   = (ushort*)(wsb + 69500928);    //  6,291,456 (bf16 [96][64][512])
  ushort* cqT   = (ushort*)(wsb + 75792384);    //  6,291,456
  ushort* ctx   = (ushort*)(wsb + 82083840);    // 18,874,368
  ushort* vt    = (ushort*)(wsb + 100958208);   // 18,874,368
  ushort* ctxln = vt;                           // alias: disjoint live ranges
  ushort* wvb   = (ushort*)(wsb + 119832576);   //  7,077,888
  ushort* wqkb  = (ushort*)(wsb + 126910464);   //  2,359,296
  ushort* wob   = (ushort*)(wsb + 129269760);   //  3,538,944  -> total ~132.8 MB

  embed_ln_kernel<<<S*B, 256, 0, stream>>>(ids, wemb, x);
  rel_ln_kernel<<<63, 256, 0, stream>>>(rele, rlw, rlb, relb);

  for(int l=0; l<NL; l++){
    const float* Wv_l  = Wv  + (size_t)l * (2*II) * H;
    const float* Wqk_l = Wqk + (size_t)l * (2*H) * H;
    const float* bqk_l = bqk + (size_t)l * (2*H);
    const float* Wo_l  = Wo  + (size_t)l * H * II;
    const float* ls_l  = lskip + (size_t)l * II;

    f2b_kernel<<<(2*II*H)/1024, 256, 0, stream>>>(Wv_l, wvb);
    f2b_kernel<<<(2*H*H)/1024, 256, 0, stream>>>(Wqk_l, wqkb);
    f2b_kernel<<<(H*II)/1024, 256, 0, stream>>>(Wo_l, wob);

    ln_x_kernel<<<S*B, 256, 0, stream>>>(x, h);
    gemm128<1><<<dim3((2*II)/128, (S*B)/128), 256, 0, stream>>>(h, wvb, nullptr, vg, S*B, 2*II, H);
    gemm128<1><<<dim3((2*H)/128, (S*B)/128), 256, 0, stream>>>(h, wqkb, bqk_l, qk, S*B, 2*H, H);
    gemm_nt64<<<dim3((2*H)/64, 1), 256, 0, stream>>>(relb, wqkb, bqk_l, posb, 63, 2*H, H);
    cpq_mfma2_kernel<<<dim3(S/128, B*NH, 2), 256, 0, stream>>>(qk, posb, cpT, cqT);
    vt_kernel<<<dim3(S/32, NH, B), 256, 0, stream>>>(vg, vt);
    attn_kernel<<<dim3(S/16, NH, B), 256, 0, stream>>>(qk, vt, cpT, cqT, pidx, ctx);
    glu_ln_kernel<<<S*B, 256, 0, stream>>>(ctx, vg, ls_l, ctxln);
    gemm128<2><<<dim3(H/128, (S*B)/128), 256, 0, stream>>>(ctxln, wob, nullptr, x, S*B, H, II);
  }
  copy_kernel<<<(S*B*H)/1024, 256, 0, stream>>>(x, (float*)d_out);
}